// Round 1
// baseline (545.543 us; speedup 1.0000x reference)
//
#include <hip/hip_runtime.h>
#include <math.h>

#define IN_F 512
#define C1 16          // 4 heads * 4 dims
#define OUTF 128
#define NEG_SLOPE 0.2f

#define P1_BM 256
#define P1_BK 32

// ---------------- layer 1 projection: h1 = x @ W1, el1/er1 epilogue ----------------
__global__ __launch_bounds__(256) void k_proj1(
    const float* __restrict__ x, const float* __restrict__ w,
    const float* __restrict__ al, const float* __restrict__ ar,
    float* __restrict__ h1, float* __restrict__ el1, float* __restrict__ er1, int n)
{
  __shared__ float xs[P1_BM * P1_BK];   // swizzled: [r*32 + (k ^ ((r&7)<<2))]
  __shared__ float wT[C1 * P1_BK];      // swizzled: [c*32 + (k ^ ((c&7)<<2))]
  const int t = threadIdx.x;
  const int rg = t >> 2;                // 0..63  -> rows rg, rg+64, rg+128, rg+192
  const int cg = t & 3;                 // head (4 cols)
  const int rowBase = blockIdx.x * P1_BM;
  float acc[4][4];
#pragma unroll
  for (int i = 0; i < 4; ++i)
#pragma unroll
    for (int j = 0; j < 4; ++j) acc[i][j] = 0.f;

  for (int k0 = 0; k0 < IN_F; k0 += P1_BK) {
#pragma unroll
    for (int i = 0; i < 8; ++i) {       // stage x tile: 256x32 floats
      int f4 = t + i * 256;
      int r = f4 >> 3;
      int k4 = (f4 & 7) << 2;
      int row = rowBase + r;
      float4 v = make_float4(0.f, 0.f, 0.f, 0.f);
      if (row < n) v = *(const float4*)&x[(size_t)row * IN_F + k0 + k4];
      *(float4*)&xs[r * P1_BK + (k4 ^ ((r & 7) << 2))] = v;
    }
#pragma unroll
    for (int i = 0; i < 2; ++i) {       // stage W^T tile: 32x16
      int f = t + i * 256;
      int kk = f >> 4;
      int c = f & 15;
      wT[c * P1_BK + (kk ^ ((c & 7) << 2))] = w[(k0 + kk) * C1 + c];
    }
    __syncthreads();
#pragma unroll
    for (int kk = 0; kk < P1_BK; kk += 4) {
      float4 xv[4], wv[4];
#pragma unroll
      for (int i = 0; i < 4; ++i) {
        int r = rg + 64 * i;
        xv[i] = *(const float4*)&xs[r * P1_BK + (kk ^ ((r & 7) << 2))];
      }
#pragma unroll
      for (int j = 0; j < 4; ++j) {
        int c = cg * 4 + j;
        wv[j] = *(const float4*)&wT[c * P1_BK + (kk ^ ((c & 7) << 2))];
      }
#pragma unroll
      for (int i = 0; i < 4; ++i)
#pragma unroll
        for (int j = 0; j < 4; ++j)
          acc[i][j] += xv[i].x * wv[j].x + xv[i].y * wv[j].y
                     + xv[i].z * wv[j].z + xv[i].w * wv[j].w;
    }
    __syncthreads();
  }

  float alv[4], arv[4];
#pragma unroll
  for (int j = 0; j < 4; ++j) { alv[j] = al[cg * 4 + j]; arv[j] = ar[cg * 4 + j]; }
#pragma unroll
  for (int i = 0; i < 4; ++i) {
    int row = rowBase + rg + 64 * i;
    if (row < n) {
      *(float4*)&h1[(size_t)row * C1 + cg * 4] =
          make_float4(acc[i][0], acc[i][1], acc[i][2], acc[i][3]);
      float e_l = acc[i][0]*alv[0] + acc[i][1]*alv[1] + acc[i][2]*alv[2] + acc[i][3]*alv[3];
      float e_r = acc[i][0]*arv[0] + acc[i][1]*arv[1] + acc[i][2]*arv[2] + acc[i][3]*arv[3];
      el1[row * 4 + cg] = e_l;
      er1[row * 4 + cg] = e_r;
    }
  }
}

// ---------------- CSR build ----------------
__global__ void k_zero(int* __restrict__ p, int n) {
  int i = blockIdx.x * blockDim.x + threadIdx.x;
  if (i < n) p[i] = 0;
}

__global__ void k_hist(const int* __restrict__ dst, int* __restrict__ deg, int e) {
  int i = blockIdx.x * blockDim.x + threadIdx.x;
  if (i < e) atomicAdd(&deg[dst[i]], 1);
}

#define SCAN_TILE 2048
__global__ __launch_bounds__(256) void k_scanA(const int* __restrict__ deg,
                                               int* __restrict__ offs,
                                               int* __restrict__ part, int n) {
  __shared__ int sums[256];
  int tile = blockIdx.x;
  int t = threadIdx.x;
  int idx0 = tile * SCAN_TILE + t * 8;
  int v[8];
  int s = 0;
#pragma unroll
  for (int i = 0; i < 8; ++i) {
    int id = idx0 + i;
    int d = (id < n) ? deg[id] : 0;
    v[i] = s; s += d;
  }
  sums[t] = s;
  __syncthreads();
  for (int off = 1; off < 256; off <<= 1) {
    int x = (t >= off) ? sums[t - off] : 0;
    __syncthreads();
    sums[t] += x;
    __syncthreads();
  }
  int thrExcl = (t > 0) ? sums[t - 1] : 0;
  if (t == 255) part[tile] = sums[255];
#pragma unroll
  for (int i = 0; i < 8; ++i) {
    int id = idx0 + i;
    if (id < n) offs[id] = thrExcl + v[i];
  }
}

__global__ void k_scanB(int* __restrict__ part, int nt) {
  int t = threadIdx.x;  // 64 threads, nt <= 64
  int v = (t < nt) ? part[t] : 0;
  int orig = v;
  for (int off = 1; off < 64; off <<= 1) {
    int u = __shfl_up(v, off);
    if (t >= off) v += u;
  }
  if (t < nt) part[t] = v - orig;   // exclusive
}

__global__ void k_scanC(int* __restrict__ offs, const int* __restrict__ part,
                        int* __restrict__ cursor, int n, int total) {
  int i = blockIdx.x * blockDim.x + threadIdx.x;
  if (i < n) {
    int v = offs[i] + part[i / SCAN_TILE];
    offs[i] = v;
    cursor[i] = v;
  }
  if (i == n) offs[n] = total;
}

__global__ void k_scatter(const int* __restrict__ src, const int* __restrict__ dst,
                          int* __restrict__ cursor, int* __restrict__ csr_src, int e) {
  int i = blockIdx.x * blockDim.x + threadIdx.x;
  if (i < e) {
    int p = atomicAdd(&cursor[dst[i]], 1);
    csr_src[p] = src[i];
  }
}

// ---------------- layer 1 aggregation + mean + relu ----------------
__global__ void k_agg1(const int* __restrict__ offs, const int* __restrict__ csr_src,
                       const float* __restrict__ h1, const float* __restrict__ el1,
                       const float* __restrict__ er1, const float* __restrict__ bias1,
                       float* __restrict__ h2in, int n) {
  int tid = blockIdx.x * blockDim.x + threadIdx.x;
  if (tid >= 4 * n) return;
  int nn = tid >> 2, h = tid & 3;
  int beg = offs[nn], end = offs[nn + 1];
  float ernh = er1[tid];
  float den = 0.f, a0 = 0.f, a1 = 0.f, a2 = 0.f, a3 = 0.f;
  for (int j = beg; j < end; ++j) {
    int s = csr_src[j];
    float e = el1[s * 4 + h] + ernh;
    e = (e > 0.f) ? e : NEG_SLOPE * e;
    float wgt = __expf(e);            // no max-subtraction: ratio is shift-invariant
    den += wgt;
    float4 hv = *(const float4*)&h1[(size_t)s * C1 + h * 4];
    a0 += wgt * hv.x; a1 += wgt * hv.y; a2 += wgt * hv.z; a3 += wgt * hv.w;
  }
  float mb = 0.25f * (bias1[h*4] + bias1[h*4+1] + bias1[h*4+2] + bias1[h*4+3]);
  float v = (end > beg) ? 0.25f * (a0 + a1 + a2 + a3) / den : 0.f;
  v += mb;
  h2in[tid] = (v > 0.f) ? v : 0.f;
}

// ---------------- layer 2 projection + el2/er2 ----------------
__global__ __launch_bounds__(128) void k_proj2(const float* __restrict__ h2in,
                                               const float* __restrict__ w2,
                                               const float* __restrict__ al2,
                                               const float* __restrict__ ar2,
                                               float* __restrict__ h2p,
                                               float* __restrict__ el2,
                                               float* __restrict__ er2, int n) {
  int nn = blockIdx.x;
  int c = threadIdx.x;                 // 0..127
  float x0 = h2in[nn * 4 + 0], x1 = h2in[nn * 4 + 1];
  float x2 = h2in[nn * 4 + 2], x3 = h2in[nn * 4 + 3];
  float v = x0 * w2[c] + x1 * w2[128 + c] + x2 * w2[256 + c] + x3 * w2[384 + c];
  h2p[(size_t)nn * OUTF + c] = v;
  float pl = v * al2[c], pr = v * ar2[c];
  int lane = threadIdx.x & 63, wid = threadIdx.x >> 6;
#pragma unroll
  for (int off = 32; off > 0; off >>= 1) {
    pl += __shfl_down(pl, off);
    pr += __shfl_down(pr, off);
  }
  __shared__ float redL[2], redR[2];
  if (lane == 0) { redL[wid] = pl; redR[wid] = pr; }
  __syncthreads();
  if (threadIdx.x == 0) {
    el2[nn] = redL[0] + redL[1];
    er2[nn] = redR[0] + redR[1];
  }
}

// ---------------- layer 2 aggregation: wave per node ----------------
__global__ __launch_bounds__(256) void k_agg2(const int* __restrict__ offs,
                                              const int* __restrict__ csr_src,
                                              const float* __restrict__ h2p,
                                              const float* __restrict__ el2,
                                              const float* __restrict__ er2,
                                              const float* __restrict__ bias2,
                                              float* __restrict__ out, int n) {
  int node = blockIdx.x * 4 + (threadIdx.x >> 6);
  if (node >= n) return;
  int lane = threadIdx.x & 63;
  int beg = offs[node], end = offs[node + 1];
  float ern = er2[node];
  float ax = 0.f, ay = 0.f, den = 0.f;
  for (int j = beg; j < end; ++j) {
    int s = csr_src[j];               // wave-uniform broadcast load
    float e = el2[s] + ern;
    e = (e > 0.f) ? e : NEG_SLOPE * e;
    float wgt = __expf(e);
    den += wgt;
    float2 v = *(const float2*)&h2p[(size_t)s * OUTF + lane * 2];
    ax += wgt * v.x; ay += wgt * v.y;
  }
  float inv = (end > beg) ? 1.0f / den : 0.f;
  float2 b = *(const float2*)&bias2[lane * 2];
  float2 o;
  o.x = ax * inv + b.x;
  o.y = ay * inv + b.y;
  *(float2*)&out[(size_t)node * OUTF + lane * 2] = o;
}

// ---------------- launch ----------------
extern "C" void kernel_launch(void* const* d_in, const int* in_sizes, int n_in,
                              void* d_out, int out_size, void* d_ws, size_t ws_size,
                              hipStream_t stream) {
  const float* nfeats = (const float*)d_in[0];
  const int*   srcp   = (const int*)d_in[2];
  const int*   dstp   = (const int*)d_in[3];
  const float* fc1    = (const float*)d_in[4];
  const float* al1    = (const float*)d_in[5];
  const float* ar1    = (const float*)d_in[6];
  const float* bias1  = (const float*)d_in[7];
  const float* fc2    = (const float*)d_in[8];
  const float* al2    = (const float*)d_in[9];
  const float* ar2    = (const float*)d_in[10];
  const float* bias2  = (const float*)d_in[11];

  const int N = in_sizes[0] / IN_F;     // 100000
  const int E = in_sizes[2];            // 1600000

  float* ws   = (float*)d_ws;
  float* h1   = ws;                          // 16N
  float* el1  = h1 + (size_t)16 * N;         // 4N
  float* er1  = el1 + (size_t)4 * N;         // 4N
  float* h2in = er1 + (size_t)4 * N;         // 4N
  float* h2p  = h2in + (size_t)4 * N;        // 128N
  float* el2  = h2p + (size_t)128 * N;       // N
  float* er2  = el2 + N;                     // N
  int* deg    = (int*)(er2 + N);             // N
  int* offs   = deg + N;                     // N+1
  int* part   = offs + (N + 1);              // 64
  int* cursor = part + 64;                   // N
  int* csrs   = cursor + N;                  // E

  const int nTiles = (N + SCAN_TILE - 1) / SCAN_TILE;  // 49 <= 64

  k_zero<<<(N + 255) / 256, 256, 0, stream>>>(deg, N);
  k_proj1<<<(N + P1_BM - 1) / P1_BM, 256, 0, stream>>>(nfeats, fc1, al1, ar1,
                                                       h1, el1, er1, N);
  k_hist<<<(E + 255) / 256, 256, 0, stream>>>(dstp, deg, E);
  k_scanA<<<nTiles, 256, 0, stream>>>(deg, offs, part, N);
  k_scanB<<<1, 64, 0, stream>>>(part, nTiles);
  k_scanC<<<(N + 1 + 255) / 256, 256, 0, stream>>>(offs, part, cursor, N, E);
  k_scatter<<<(E + 255) / 256, 256, 0, stream>>>(srcp, dstp, cursor, csrs, E);
  k_agg1<<<(4 * N + 255) / 256, 256, 0, stream>>>(offs, csrs, h1, el1, er1,
                                                  bias1, h2in, N);
  k_proj2<<<N, 128, 0, stream>>>(h2in, fc2, al2, ar2, h2p, el2, er2, N);
  k_agg2<<<(N + 3) / 4, 256, 0, stream>>>(offs, csrs, h2p, el2, er2, bias2,
                                          (float*)d_out, N);
}

// Round 2
// 399.690 us; speedup vs baseline: 1.3649x; 1.3649x over previous
//
#include <hip/hip_runtime.h>
#include <math.h>

#define IN_F 512
#define C1 16          // 4 heads * 4 dims
#define OUTF 128
#define NEG_SLOPE 0.2f

#define P1_BM 128
#define P1_BK 32

// ---------------- layer 1 projection: h1 = x @ W1, el1/er1 epilogue ----------------
__global__ __launch_bounds__(256) void k_proj1(
    const float* __restrict__ x, const float* __restrict__ w,
    const float* __restrict__ al, const float* __restrict__ ar,
    float* __restrict__ h1, float* __restrict__ el1, float* __restrict__ er1, int n)
{
  __shared__ float xs[P1_BM * P1_BK];   // swizzled: [r*32 + (k ^ ((r&7)<<2))]
  __shared__ float wT[C1 * P1_BK];      // swizzled: [c*32 + (k ^ ((c&7)<<2))]
  const int t = threadIdx.x;
  const int rg = t >> 2;                // 0..63  -> rows rg, rg+64
  const int cg = t & 3;                 // head (4 cols)
  const int rowBase = blockIdx.x * P1_BM;
  float acc[2][4];
#pragma unroll
  for (int i = 0; i < 2; ++i)
#pragma unroll
    for (int j = 0; j < 4; ++j) acc[i][j] = 0.f;

  for (int k0 = 0; k0 < IN_F; k0 += P1_BK) {
#pragma unroll
    for (int i = 0; i < 4; ++i) {       // stage x tile: 128x32 floats
      int f4 = t + i * 256;
      int r = f4 >> 3;
      int k4 = (f4 & 7) << 2;
      int row = rowBase + r;
      float4 v = make_float4(0.f, 0.f, 0.f, 0.f);
      if (row < n) v = *(const float4*)&x[(size_t)row * IN_F + k0 + k4];
      *(float4*)&xs[r * P1_BK + (k4 ^ ((r & 7) << 2))] = v;
    }
#pragma unroll
    for (int i = 0; i < 2; ++i) {       // stage W^T tile: 32x16
      int f = t + i * 256;
      int kk = f >> 4;
      int c = f & 15;
      wT[c * P1_BK + (kk ^ ((c & 7) << 2))] = w[(k0 + kk) * C1 + c];
    }
    __syncthreads();
#pragma unroll
    for (int kk = 0; kk < P1_BK; kk += 4) {
      float4 xv[2], wv[4];
#pragma unroll
      for (int i = 0; i < 2; ++i) {
        int r = rg + 64 * i;
        xv[i] = *(const float4*)&xs[r * P1_BK + (kk ^ ((r & 7) << 2))];
      }
#pragma unroll
      for (int j = 0; j < 4; ++j) {
        int c = cg * 4 + j;
        wv[j] = *(const float4*)&wT[c * P1_BK + (kk ^ ((c & 7) << 2))];
      }
#pragma unroll
      for (int i = 0; i < 2; ++i)
#pragma unroll
        for (int j = 0; j < 4; ++j)
          acc[i][j] += xv[i].x * wv[j].x + xv[i].y * wv[j].y
                     + xv[i].z * wv[j].z + xv[i].w * wv[j].w;
    }
    __syncthreads();
  }

  float alv[4], arv[4];
#pragma unroll
  for (int j = 0; j < 4; ++j) { alv[j] = al[cg * 4 + j]; arv[j] = ar[cg * 4 + j]; }
#pragma unroll
  for (int i = 0; i < 2; ++i) {
    int row = rowBase + rg + 64 * i;
    if (row < n) {
      *(float4*)&h1[(size_t)row * C1 + cg * 4] =
          make_float4(acc[i][0], acc[i][1], acc[i][2], acc[i][3]);
      float e_l = acc[i][0]*alv[0] + acc[i][1]*alv[1] + acc[i][2]*alv[2] + acc[i][3]*alv[3];
      float e_r = acc[i][0]*arv[0] + acc[i][1]*arv[1] + acc[i][2]*arv[2] + acc[i][3]*arv[3];
      el1[row * 4 + cg] = e_l;
      er1[row * 4 + cg] = e_r;
    }
  }
}

// ---------------- CSR build ----------------
__global__ void k_zero(int* __restrict__ p, int n) {
  int i = blockIdx.x * blockDim.x + threadIdx.x;
  if (i < n) p[i] = 0;
}

__global__ void k_hist(const int* __restrict__ dst, int* __restrict__ deg, int e) {
  int i = blockIdx.x * blockDim.x + threadIdx.x;
  if (i < e) atomicAdd(&deg[dst[i]], 1);
}

#define SCAN_TILE 2048
__global__ __launch_bounds__(256) void k_scanA(const int* __restrict__ deg,
                                               int* __restrict__ offs,
                                               int* __restrict__ part, int n) {
  __shared__ int sums[256];
  int tile = blockIdx.x;
  int t = threadIdx.x;
  int idx0 = tile * SCAN_TILE + t * 8;
  int v[8];
  int s = 0;
#pragma unroll
  for (int i = 0; i < 8; ++i) {
    int id = idx0 + i;
    int d = (id < n) ? deg[id] : 0;
    v[i] = s; s += d;
  }
  sums[t] = s;
  __syncthreads();
  for (int off = 1; off < 256; off <<= 1) {
    int x = (t >= off) ? sums[t - off] : 0;
    __syncthreads();
    sums[t] += x;
    __syncthreads();
  }
  int thrExcl = (t > 0) ? sums[t - 1] : 0;
  if (t == 255) part[tile] = sums[255];
#pragma unroll
  for (int i = 0; i < 8; ++i) {
    int id = idx0 + i;
    if (id < n) offs[id] = thrExcl + v[i];
  }
}

__global__ void k_scanB(int* __restrict__ part, int nt) {
  int t = threadIdx.x;  // 64 threads, nt <= 64
  int v = (t < nt) ? part[t] : 0;
  int orig = v;
  for (int off = 1; off < 64; off <<= 1) {
    int u = __shfl_up(v, off);
    if (t >= off) v += u;
  }
  if (t < nt) part[t] = v - orig;   // exclusive
}

__global__ void k_scanC(int* __restrict__ offs, const int* __restrict__ part,
                        int* __restrict__ cursor, int n, int total) {
  int i = blockIdx.x * blockDim.x + threadIdx.x;
  if (i < n) {
    int v = offs[i] + part[i / SCAN_TILE];
    offs[i] = v;
    cursor[i] = v;
  }
  if (i == n) offs[n] = total;
}

__global__ void k_scatter(const int* __restrict__ src, const int* __restrict__ dst,
                          int* __restrict__ cursor, int* __restrict__ csr_src, int e) {
  int i = blockIdx.x * blockDim.x + threadIdx.x;
  if (i < e) {
    int p = atomicAdd(&cursor[dst[i]], 1);
    csr_src[p] = src[i];
  }
}

// ---------------- prep: fold al2/ar2 through W2 (h2p never materialized) ----------------
__global__ void k_prep(const float* __restrict__ w2, const float* __restrict__ al2,
                       const float* __restrict__ ar2, float* __restrict__ w2al,
                       float* __restrict__ w2ar) {
  int t = threadIdx.x;                 // 8 threads: h = t>>1, sel = t&1
  if (t < 8) {
    int h = t >> 1;
    const float* a = (t & 1) ? ar2 : al2;
    float s = 0.f;
#pragma unroll 16
    for (int c = 0; c < OUTF; ++c) s += w2[h * OUTF + c] * a[c];
    if (t & 1) w2ar[h] = s; else w2al[h] = s;
  }
}

// ---------------- layer 1 aggregation + mean + relu + el2/er2 epilogue ----------------
__global__ void k_agg1(const int* __restrict__ offs, const int* __restrict__ csr_src,
                       const float* __restrict__ h1, const float* __restrict__ el1,
                       const float* __restrict__ er1, const float* __restrict__ bias1,
                       const float* __restrict__ w2al, const float* __restrict__ w2ar,
                       float* __restrict__ h2in, float* __restrict__ el2,
                       float* __restrict__ er2, int n) {
  int tid = blockIdx.x * blockDim.x + threadIdx.x;
  int nn = tid >> 2, h = tid & 3;
  bool active = nn < n;
  float v = 0.f;
  if (active) {
    int beg = offs[nn], end = offs[nn + 1];
    float ernh = er1[tid];
    float den = 0.f, a0 = 0.f, a1 = 0.f, a2 = 0.f, a3 = 0.f;
    for (int j = beg; j < end; ++j) {
      int s = csr_src[j];
      float e = el1[s * 4 + h] + ernh;
      e = (e > 0.f) ? e : NEG_SLOPE * e;
      float wgt = __expf(e);          // no max-subtraction: ratio is shift-invariant
      den += wgt;
      float4 hv = *(const float4*)&h1[(size_t)s * C1 + h * 4];
      a0 += wgt * hv.x; a1 += wgt * hv.y; a2 += wgt * hv.z; a3 += wgt * hv.w;
    }
    float mb = 0.25f * (bias1[h*4] + bias1[h*4+1] + bias1[h*4+2] + bias1[h*4+3]);
    v = (end > beg) ? 0.25f * (a0 + a1 + a2 + a3) / den : 0.f;
    v += mb;
    v = (v > 0.f) ? v : 0.f;
    h2in[tid] = v;
  }
  // el2[n] = h2in[n] . (W2 @ al2) via 4-lane butterfly (lanes of one node adjacent)
  float pl = v * w2al[h];
  float pr = v * w2ar[h];
  pl += __shfl_xor(pl, 1); pl += __shfl_xor(pl, 2);
  pr += __shfl_xor(pr, 1); pr += __shfl_xor(pr, 2);
  if (active && h == 0) el2[nn] = pl;
  if (active && h == 1) er2[nn] = pr;
}

// ---------------- layer 2 aggregation in 4-dim input space ----------------
__global__ void k_agg2low(const int* __restrict__ offs, const int* __restrict__ csr_src,
                          const float* __restrict__ h2in, const float* __restrict__ el2,
                          const float* __restrict__ er2, float* __restrict__ g4, int n) {
  int nn = blockIdx.x * blockDim.x + threadIdx.x;
  if (nn >= n) return;
  int beg = offs[nn], end = offs[nn + 1];
  float ern = er2[nn];
  float den = 0.f, a0 = 0.f, a1 = 0.f, a2 = 0.f, a3 = 0.f;
  for (int j = beg; j < end; ++j) {
    int s = csr_src[j];
    float e = el2[s] + ern;
    e = (e > 0.f) ? e : NEG_SLOPE * e;
    float wgt = __expf(e);
    den += wgt;
    float4 hv = *(const float4*)&h2in[(size_t)s * 4];
    a0 += wgt * hv.x; a1 += wgt * hv.y; a2 += wgt * hv.z; a3 += wgt * hv.w;
  }
  float inv = (end > beg) ? 1.0f / den : 0.f;
  *(float4*)&g4[(size_t)nn * 4] =
      make_float4(a0 * inv, a1 * inv, a2 * inv, a3 * inv);
}

// ---------------- output projection: out = g4 @ W2 + bias2 ----------------
__global__ __launch_bounds__(256) void k_out(const float* __restrict__ g4,
                                             const float* __restrict__ w2,
                                             const float* __restrict__ bias2,
                                             float* __restrict__ out, int n) {
  int node = blockIdx.x * 4 + (threadIdx.x >> 6);
  if (node >= n) return;
  int lane = threadIdx.x & 63;
  float4 g = *(const float4*)&g4[(size_t)node * 4];   // wave-uniform broadcast
  int c = lane * 2;
  float2 w0 = *(const float2*)&w2[c];
  float2 w1 = *(const float2*)&w2[OUTF + c];
  float2 w2v = *(const float2*)&w2[2 * OUTF + c];
  float2 w3 = *(const float2*)&w2[3 * OUTF + c];
  float2 b = *(const float2*)&bias2[c];
  float2 o;
  o.x = g.x * w0.x + g.y * w1.x + g.z * w2v.x + g.w * w3.x + b.x;
  o.y = g.x * w0.y + g.y * w1.y + g.z * w2v.y + g.w * w3.y + b.y;
  *(float2*)&out[(size_t)node * OUTF + c] = o;
}

// ---------------- launch ----------------
extern "C" void kernel_launch(void* const* d_in, const int* in_sizes, int n_in,
                              void* d_out, int out_size, void* d_ws, size_t ws_size,
                              hipStream_t stream) {
  const float* nfeats = (const float*)d_in[0];
  const int*   srcp   = (const int*)d_in[2];
  const int*   dstp   = (const int*)d_in[3];
  const float* fc1    = (const float*)d_in[4];
  const float* al1    = (const float*)d_in[5];
  const float* ar1    = (const float*)d_in[6];
  const float* bias1  = (const float*)d_in[7];
  const float* fc2    = (const float*)d_in[8];
  const float* al2    = (const float*)d_in[9];
  const float* ar2    = (const float*)d_in[10];
  const float* bias2  = (const float*)d_in[11];

  const int N = in_sizes[0] / IN_F;     // 100000
  const int E = in_sizes[2];            // 1600000

  float* ws   = (float*)d_ws;
  float* h1   = ws;                          // 16N
  float* el1  = h1 + (size_t)16 * N;         // 4N
  float* er1  = el1 + (size_t)4 * N;         // 4N
  float* h2in = er1 + (size_t)4 * N;         // 4N
  float* g4   = h2in + (size_t)4 * N;        // 4N
  float* el2  = g4 + (size_t)4 * N;          // N
  float* er2  = el2 + N;                     // N
  float* w2al = er2 + N;                     // 4
  float* w2ar = w2al + 4;                    // 4
  int* deg    = (int*)(w2ar + 4);            // N
  int* offs   = deg + N;                     // N+1
  int* part   = offs + (N + 1);              // 64
  int* cursor = part + 64;                   // N
  int* csrs   = cursor + N;                  // E

  const int nTiles = (N + SCAN_TILE - 1) / SCAN_TILE;  // 49 <= 64

  k_zero<<<(N + 255) / 256, 256, 0, stream>>>(deg, N);
  k_proj1<<<(N + P1_BM - 1) / P1_BM, 256, 0, stream>>>(nfeats, fc1, al1, ar1,
                                                       h1, el1, er1, N);
  k_hist<<<(E + 255) / 256, 256, 0, stream>>>(dstp, deg, E);
  k_scanA<<<nTiles, 256, 0, stream>>>(deg, offs, part, N);
  k_scanB<<<1, 64, 0, stream>>>(part, nTiles);
  k_scanC<<<(N + 1 + 255) / 256, 256, 0, stream>>>(offs, part, cursor, N, E);
  k_scatter<<<(E + 255) / 256, 256, 0, stream>>>(srcp, dstp, cursor, csrs, E);
  k_prep<<<1, 64, 0, stream>>>(fc2, al2, ar2, w2al, w2ar);
  k_agg1<<<(4 * N + 255) / 256, 256, 0, stream>>>(offs, csrs, h1, el1, er1, bias1,
                                                  w2al, w2ar, h2in, el2, er2, N);
  k_agg2low<<<(N + 255) / 256, 256, 0, stream>>>(offs, csrs, h2in, el2, er2, g4, N);
  k_out<<<(N + 3) / 4, 256, 0, stream>>>(g4, fc2, bias2, (float*)d_out, N);
}

// Round 3
// 354.423 us; speedup vs baseline: 1.5392x; 1.1277x over previous
//
#include <hip/hip_runtime.h>
#include <math.h>

#define IN_F 512
#define C1 16          // 4 heads * 4 dims
#define OUTF 128
#define NEG_SLOPE 0.2f

#define BKT 16         // k-tile depth
#define PROWS 256      // rows per block (1 per thread)
#define XPITCH 20      // 16 + 4 pad floats per row => read granule (5r+kq)&7, even spread

// ---------------- layer 1 projection: h1 = x @ W1, el1/er1 epilogue ----------------
// W is read via wave-uniform global loads (-> s_load, scalar K$); only x is LDS-staged.
__global__ __launch_bounds__(256) void k_proj1(
    const float* __restrict__ x, const float* __restrict__ w,
    const float* __restrict__ al, const float* __restrict__ ar,
    float* __restrict__ h1, float* __restrict__ el1, float* __restrict__ er1, int n)
{
  __shared__ float xs[PROWS * XPITCH];
  const int t = threadIdx.x;
  const int rowBase = blockIdx.x * PROWS;
  const int myRow = rowBase + t;
  float acc[16];
#pragma unroll
  for (int c = 0; c < 16; ++c) acc[c] = 0.f;

  // prefetch tile 0 into registers
  float4 st[4];
#pragma unroll
  for (int i = 0; i < 4; ++i) {
    int f4 = t + i * 256;
    int r = f4 >> 2, kq = f4 & 3;
    int row = rowBase + r;
    st[i] = (row < n) ? *(const float4*)&x[(size_t)row * IN_F + kq * 4]
                      : make_float4(0.f, 0.f, 0.f, 0.f);
  }

  for (int tile = 0; tile < IN_F / BKT; ++tile) {
    __syncthreads();                      // previous compute finished reading xs
#pragma unroll
    for (int i = 0; i < 4; ++i) {
      int f4 = t + i * 256;
      int r = f4 >> 2, kq = f4 & 3;
      *(float4*)&xs[r * XPITCH + kq * 4] = st[i];
    }
    if (tile + 1 < IN_F / BKT) {          // issue next tile's global loads (overlap compute)
      int k0 = (tile + 1) * BKT;
#pragma unroll
      for (int i = 0; i < 4; ++i) {
        int f4 = t + i * 256;
        int r = f4 >> 2, kq = f4 & 3;
        int row = rowBase + r;
        st[i] = (row < n) ? *(const float4*)&x[(size_t)row * IN_F + k0 + kq * 4]
                          : make_float4(0.f, 0.f, 0.f, 0.f);
      }
    }
    __syncthreads();
    const int k0 = tile * BKT;
#pragma unroll
    for (int kq = 0; kq < 4; ++kq) {
      float4 xv = *(const float4*)&xs[t * XPITCH + kq * 4];
      const float* __restrict__ wk = &w[(k0 + kq * 4) * C1];   // wave-uniform -> s_load
      float xj[4] = {xv.x, xv.y, xv.z, xv.w};
#pragma unroll
      for (int j = 0; j < 4; ++j)
#pragma unroll
        for (int c = 0; c < 16; ++c)
          acc[c] = fmaf(xj[j], wk[j * C1 + c], acc[c]);
    }
  }

  if (myRow < n) {
#pragma unroll
    for (int i = 0; i < 4; ++i)
      *(float4*)&h1[(size_t)myRow * C1 + i * 4] =
          make_float4(acc[i*4], acc[i*4+1], acc[i*4+2], acc[i*4+3]);
    float el_[4], er_[4];
#pragma unroll
    for (int h = 0; h < 4; ++h) {
      float sl = 0.f, sr = 0.f;
#pragma unroll
      for (int j = 0; j < 4; ++j) {
        sl = fmaf(acc[h*4+j], al[h*4+j], sl);   // al/ar uniform -> s_load
        sr = fmaf(acc[h*4+j], ar[h*4+j], sr);
      }
      el_[h] = sl; er_[h] = sr;
    }
    *(float4*)&el1[(size_t)myRow * 4] = make_float4(el_[0], el_[1], el_[2], el_[3]);
    *(float4*)&er1[(size_t)myRow * 4] = make_float4(er_[0], er_[1], er_[2], er_[3]);
  }
}

// ---------------- CSR build ----------------
__global__ void k_zero(int* __restrict__ p, int n) {
  int i = blockIdx.x * blockDim.x + threadIdx.x;
  if (i < n) p[i] = 0;
}

__global__ void k_hist(const int* __restrict__ dst, int* __restrict__ deg, int e) {
  int i = blockIdx.x * blockDim.x + threadIdx.x;
  if (i < e) atomicAdd(&deg[dst[i]], 1);
}

#define SCAN_TILE 2048
__global__ __launch_bounds__(256) void k_scanA(const int* __restrict__ deg,
                                               int* __restrict__ offs,
                                               int* __restrict__ part, int n) {
  __shared__ int sums[256];
  int tile = blockIdx.x;
  int t = threadIdx.x;
  int idx0 = tile * SCAN_TILE + t * 8;
  int v[8];
  int s = 0;
#pragma unroll
  for (int i = 0; i < 8; ++i) {
    int id = idx0 + i;
    int d = (id < n) ? deg[id] : 0;
    v[i] = s; s += d;
  }
  sums[t] = s;
  __syncthreads();
  for (int off = 1; off < 256; off <<= 1) {
    int x = (t >= off) ? sums[t - off] : 0;
    __syncthreads();
    sums[t] += x;
    __syncthreads();
  }
  int thrExcl = (t > 0) ? sums[t - 1] : 0;
  if (t == 255) part[tile] = sums[255];
#pragma unroll
  for (int i = 0; i < 8; ++i) {
    int id = idx0 + i;
    if (id < n) offs[id] = thrExcl + v[i];
  }
}

__global__ void k_scanB(int* __restrict__ part, int nt) {
  int t = threadIdx.x;  // 64 threads, nt <= 64
  int v = (t < nt) ? part[t] : 0;
  int orig = v;
  for (int off = 1; off < 64; off <<= 1) {
    int u = __shfl_up(v, off);
    if (t >= off) v += u;
  }
  if (t < nt) part[t] = v - orig;   // exclusive
}

__global__ void k_scanC(int* __restrict__ offs, const int* __restrict__ part,
                        int* __restrict__ cursor, int n, int total) {
  int i = blockIdx.x * blockDim.x + threadIdx.x;
  if (i < n) {
    int v = offs[i] + part[i / SCAN_TILE];
    offs[i] = v;
    cursor[i] = v;
  }
  if (i == n) offs[n] = total;
}

__global__ void k_scatter(const int* __restrict__ src, const int* __restrict__ dst,
                          int* __restrict__ cursor, int* __restrict__ csr_src, int e) {
  int i = blockIdx.x * blockDim.x + threadIdx.x;
  if (i < e) {
    int p = atomicAdd(&cursor[dst[i]], 1);
    csr_src[p] = src[i];
  }
}

// ---------------- prep: fold al2/ar2 through W2 (h2p never materialized) ----------------
__global__ void k_prep(const float* __restrict__ w2, const float* __restrict__ al2,
                       const float* __restrict__ ar2, float* __restrict__ w2al,
                       float* __restrict__ w2ar) {
  int t = threadIdx.x;                 // 8 threads: h = t>>1, sel = t&1
  if (t < 8) {
    int h = t >> 1;
    const float* a = (t & 1) ? ar2 : al2;
    float s = 0.f;
#pragma unroll 16
    for (int c = 0; c < OUTF; ++c) s += w2[h * OUTF + c] * a[c];
    if (t & 1) w2ar[h] = s; else w2al[h] = s;
  }
}

// ---------------- layer 1 aggregation + mean + relu + el2/er2 epilogue ----------------
__global__ void k_agg1(const int* __restrict__ offs, const int* __restrict__ csr_src,
                       const float* __restrict__ h1, const float* __restrict__ el1,
                       const float* __restrict__ er1, const float* __restrict__ bias1,
                       const float* __restrict__ w2al, const float* __restrict__ w2ar,
                       float* __restrict__ h2in, float* __restrict__ el2,
                       float* __restrict__ er2, int n) {
  int tid = blockIdx.x * blockDim.x + threadIdx.x;
  int nn = tid >> 2, h = tid & 3;
  bool active = nn < n;
  float v = 0.f;
  if (active) {
    int beg = offs[nn], end = offs[nn + 1];
    float ernh = er1[tid];
    float den = 0.f, a0 = 0.f, a1 = 0.f, a2 = 0.f, a3 = 0.f;
    for (int j = beg; j < end; ++j) {
      int s = csr_src[j];
      float e = el1[s * 4 + h] + ernh;
      e = (e > 0.f) ? e : NEG_SLOPE * e;
      float wgt = __expf(e);          // no max-subtraction: ratio is shift-invariant
      den += wgt;
      float4 hv = *(const float4*)&h1[(size_t)s * C1 + h * 4];
      a0 += wgt * hv.x; a1 += wgt * hv.y; a2 += wgt * hv.z; a3 += wgt * hv.w;
    }
    float mb = 0.25f * (bias1[h*4] + bias1[h*4+1] + bias1[h*4+2] + bias1[h*4+3]);
    v = (end > beg) ? 0.25f * (a0 + a1 + a2 + a3) / den : 0.f;
    v += mb;
    v = (v > 0.f) ? v : 0.f;
    h2in[tid] = v;
  }
  // el2[n] = h2in[n] . (W2 @ al2) via 4-lane butterfly (lanes of one node adjacent)
  float pl = v * w2al[h];
  float pr = v * w2ar[h];
  pl += __shfl_xor(pl, 1); pl += __shfl_xor(pl, 2);
  pr += __shfl_xor(pr, 1); pr += __shfl_xor(pr, 2);
  if (active && h == 0) el2[nn] = pl;
  if (active && h == 1) er2[nn] = pr;
}

// ---------------- layer 2 aggregation in 4-dim input space ----------------
__global__ void k_agg2low(const int* __restrict__ offs, const int* __restrict__ csr_src,
                          const float* __restrict__ h2in, const float* __restrict__ el2,
                          const float* __restrict__ er2, float* __restrict__ g4, int n) {
  int nn = blockIdx.x * blockDim.x + threadIdx.x;
  if (nn >= n) return;
  int beg = offs[nn], end = offs[nn + 1];
  float ern = er2[nn];
  float den = 0.f, a0 = 0.f, a1 = 0.f, a2 = 0.f, a3 = 0.f;
  for (int j = beg; j < end; ++j) {
    int s = csr_src[j];
    float e = el2[s] + ern;
    e = (e > 0.f) ? e : NEG_SLOPE * e;
    float wgt = __expf(e);
    den += wgt;
    float4 hv = *(const float4*)&h2in[(size_t)s * 4];
    a0 += wgt * hv.x; a1 += wgt * hv.y; a2 += wgt * hv.z; a3 += wgt * hv.w;
  }
  float inv = (end > beg) ? 1.0f / den : 0.f;
  *(float4*)&g4[(size_t)nn * 4] =
      make_float4(a0 * inv, a1 * inv, a2 * inv, a3 * inv);
}

// ---------------- output projection: out = g4 @ W2 + bias2 ----------------
__global__ __launch_bounds__(256) void k_out(const float* __restrict__ g4,
                                             const float* __restrict__ w2,
                                             const float* __restrict__ bias2,
                                             float* __restrict__ out, int n) {
  int node = blockIdx.x * 4 + (threadIdx.x >> 6);
  if (node >= n) return;
  int lane = threadIdx.x & 63;
  float4 g = *(const float4*)&g4[(size_t)node * 4];   // wave-uniform broadcast
  int c = lane * 2;
  float2 w0 = *(const float2*)&w2[c];
  float2 w1 = *(const float2*)&w2[OUTF + c];
  float2 w2v = *(const float2*)&w2[2 * OUTF + c];
  float2 w3 = *(const float2*)&w2[3 * OUTF + c];
  float2 b = *(const float2*)&bias2[c];
  float2 o;
  o.x = g.x * w0.x + g.y * w1.x + g.z * w2v.x + g.w * w3.x + b.x;
  o.y = g.x * w0.y + g.y * w1.y + g.z * w2v.y + g.w * w3.y + b.y;
  *(float2*)&out[(size_t)node * OUTF + c] = o;
}

// ---------------- launch ----------------
extern "C" void kernel_launch(void* const* d_in, const int* in_sizes, int n_in,
                              void* d_out, int out_size, void* d_ws, size_t ws_size,
                              hipStream_t stream) {
  const float* nfeats = (const float*)d_in[0];
  const int*   srcp   = (const int*)d_in[2];
  const int*   dstp   = (const int*)d_in[3];
  const float* fc1    = (const float*)d_in[4];
  const float* al1    = (const float*)d_in[5];
  const float* ar1    = (const float*)d_in[6];
  const float* bias1  = (const float*)d_in[7];
  const float* fc2    = (const float*)d_in[8];
  const float* al2    = (const float*)d_in[9];
  const float* ar2    = (const float*)d_in[10];
  const float* bias2  = (const float*)d_in[11];

  const int N = in_sizes[0] / IN_F;     // 100000
  const int E = in_sizes[2];            // 1600000

  float* ws   = (float*)d_ws;
  float* h1   = ws;                          // 16N
  float* el1  = h1 + (size_t)16 * N;         // 4N
  float* er1  = el1 + (size_t)4 * N;         // 4N
  float* h2in = er1 + (size_t)4 * N;         // 4N
  float* g4   = h2in + (size_t)4 * N;        // 4N
  float* el2  = g4 + (size_t)4 * N;          // N
  float* er2  = el2 + N;                     // N
  float* w2al = er2 + N;                     // 4
  float* w2ar = w2al + 4;                    // 4
  int* deg    = (int*)(w2ar + 4);            // N
  int* offs   = deg + N;                     // N+1
  int* part   = offs + (N + 1);              // 64
  int* cursor = part + 64;                   // N
  int* csrs   = cursor + N;                  // E

  const int nTiles = (N + SCAN_TILE - 1) / SCAN_TILE;  // 49 <= 64

  k_zero<<<(N + 255) / 256, 256, 0, stream>>>(deg, N);
  k_proj1<<<(N + PROWS - 1) / PROWS, 256, 0, stream>>>(nfeats, fc1, al1, ar1,
                                                       h1, el1, er1, N);
  k_hist<<<(E + 255) / 256, 256, 0, stream>>>(dstp, deg, E);
  k_scanA<<<nTiles, 256, 0, stream>>>(deg, offs, part, N);
  k_scanB<<<1, 64, 0, stream>>>(part, nTiles);
  k_scanC<<<(N + 1 + 255) / 256, 256, 0, stream>>>(offs, part, cursor, N, E);
  k_scatter<<<(E + 255) / 256, 256, 0, stream>>>(srcp, dstp, cursor, csrs, E);
  k_prep<<<1, 64, 0, stream>>>(fc2, al2, ar2, w2al, w2ar);
  k_agg1<<<(4 * N + 255) / 256, 256, 0, stream>>>(offs, csrs, h1, el1, er1, bias1,
                                                  w2al, w2ar, h2in, el2, er2, N);
  k_agg2low<<<(N + 255) / 256, 256, 0, stream>>>(offs, csrs, h2in, el2, er2, g4, N);
  k_out<<<(N + 3) / 4, 256, 0, stream>>>(g4, fc2, bias2, (float*)d_out, N);
}